// Round 3
// baseline (2171.577 us; speedup 1.0000x reference)
//
#include <hip/hip_runtime.h>
#include <hip/hip_bf16.h>
#include <cstdint>
#include <cstddef>

typedef __hip_bfloat16 bf16;
typedef short v8s __attribute__((ext_vector_type(8)));
typedef float v4f __attribute__((ext_vector_type(4)));

#define N_NODES 50000
#define N_HE    5000
#define N_EDGE  800000
#define N_INC   400000

// ---------------------------------------------------------------- CSR build
__global__ void zero3_kernel(int* a, int na, int* b, int nb, int* c, int nc) {
  int total = na + nb + nc;
  for (int i = blockIdx.x * blockDim.x + threadIdx.x; i < total;
       i += gridDim.x * blockDim.x) {
    if (i < na) a[i] = 0;
    else if (i < na + nb) b[i - na] = 0;
    else c[i - na - nb] = 0;
  }
}

__global__ void hist_kernel(const int* __restrict__ dst,
                            const int* __restrict__ he_node,
                            const int* __restrict__ he_edge,
                            int* cnt_dst, int* cnt_he, int* cnt_hn) {
  int i = blockIdx.x * blockDim.x + threadIdx.x;
  if (i < N_EDGE) atomicAdd(&cnt_dst[dst[i]], 1);
  if (i < N_INC) {
    atomicAdd(&cnt_he[he_edge[i]], 1);
    atomicAdd(&cnt_hn[he_node[i]], 1);
  }
}

__global__ void scales_kernel(const int* cnt_dst, const int* cnt_hn,
                              const int* cnt_he,
                              float* deg_inv, float* dinv, float* binv) {
  int i = blockIdx.x * blockDim.x + threadIdx.x;
  if (i < N_NODES) {
    int d = cnt_dst[i];
    deg_inv[i] = 1.0f / (float)(d > 1 ? d : 1);
    int h = cnt_hn[i];
    dinv[i] = h > 0 ? 1.0f / (float)h : 0.0f;
  }
  if (i < N_HE) {
    int e = cnt_he[i];
    binv[i] = e > 0 ? 1.0f / (float)e : 0.0f;
  }
}

__global__ void scan3_kernel(const int* cnt_dst, int* adj_off, int* adj_cur,
                             const int* cnt_he, int* heg_off, int* heg_cur,
                             const int* cnt_hn, int* hng_off, int* hng_cur) {
  const int* cnt; int* off; int* cur; int n;
  if (blockIdx.x == 0)      { cnt = cnt_dst; off = adj_off; cur = adj_cur; n = N_NODES; }
  else if (blockIdx.x == 1) { cnt = cnt_he;  off = heg_off; cur = heg_cur; n = N_HE; }
  else                      { cnt = cnt_hn;  off = hng_off; cur = hng_cur; n = N_NODES; }
  __shared__ int buf[1024];
  int t = threadIdx.x;
  int carry = 0;
  for (int base = 0; base < n; base += 1024) {
    int i = base + t;
    int v = (i < n) ? cnt[i] : 0;
    buf[t] = v;
    __syncthreads();
    for (int d = 1; d < 1024; d <<= 1) {
      int x = (t >= d) ? buf[t - d] : 0;
      __syncthreads();
      buf[t] += x;
      __syncthreads();
    }
    int excl = buf[t] - v;
    if (i < n) { off[i] = carry + excl; cur[i] = carry + excl; }
    int total = buf[1023];
    __syncthreads();
    carry += total;
  }
  if (t == 0) off[n] = carry;
}

__global__ void fill_kernel(const int* __restrict__ src, const int* __restrict__ dst,
                            const int* __restrict__ he_node, const int* __restrict__ he_edge,
                            int* adj_cur, int* adj_src,
                            int* heg_cur, int* heg_node,
                            int* hng_cur, int* hng_edge) {
  int i = blockIdx.x * blockDim.x + threadIdx.x;
  if (i < N_EDGE) {
    int p = atomicAdd(&adj_cur[dst[i]], 1);
    adj_src[p] = src[i];
  }
  if (i < N_INC) {
    int p = atomicAdd(&heg_cur[he_edge[i]], 1);
    heg_node[p] = he_node[i];
    int p2 = atomicAdd(&hng_cur[he_node[i]], 1);
    hng_edge[p2] = he_edge[i];
  }
}

// ---------------------------------------------------- weight hi/lo bf16 split
#define W_TOTAL 456704
__global__ void split_w_kernel(const float* s0wl, const float* s0wr,
                               const float* s1wl, const float* s1wr,
                               const float* s2wl, const float* s2wr,
                               const float* h0w, const float* h1w,
                               const float* h2w, const float* h3w,
                               const float* h4w,
                               uint16_t* hi, uint16_t* lo) {
  int i = blockIdx.x * blockDim.x + threadIdx.x;
  if (i >= W_TOTAL) return;
  const float* src; int base;
  if (i < 32768)       { src = s0wl; base = 0; }
  else if (i < 65536)  { src = s0wr; base = 32768; }
  else if (i < 131072) { src = s1wl; base = 65536; }
  else if (i < 196608) { src = s1wr; base = 131072; }
  else if (i < 206848) { src = s2wl; base = 196608; }
  else if (i < 217088) { src = s2wr; base = 206848; }
  else if (i < 249856) { src = h0w;  base = 217088; }
  else if (i < 315392) { src = h1w;  base = 249856; }
  else if (i < 380928) { src = h2w;  base = 315392; }
  else if (i < 446464) { src = h3w;  base = 380928; }
  else                 { src = h4w;  base = 446464; }
  float v = src[i - base];
  uint32_t u = __float_as_uint(v);
  uint32_t hb = (u + 0x7FFFu + ((u >> 16) & 1u)) >> 16;
  float hf = __uint_as_float(hb << 16);
  float lf = v - hf;
  uint32_t ul = __float_as_uint(lf);
  uint32_t lb = (ul + 0x7FFFu + ((ul >> 16) & 1u)) >> 16;
  hi[i] = (uint16_t)hb;
  lo[i] = (uint16_t)lb;
}

// ------------------------------------------------- CSR gather-mean, float4
__global__ void agg4_kernel(const int* __restrict__ off, const int* __restrict__ idx,
                            const float* __restrict__ scale,
                            const float* __restrict__ X, int F,
                            float* __restrict__ OUT) {
  int row = blockIdx.x;
  int t = threadIdx.x;
  int F4 = F >> 2;
  if (t >= F4) return;
  int j0 = off[row], j1 = off[row + 1];
  float sc = scale[row];
  v4f acc = {0.f, 0.f, 0.f, 0.f};
  for (int j = j0; j < j1; ++j) {
    int s = idx[j];
    v4f v = *((const v4f*)(X + (size_t)s * F) + t);
    acc += v;
  }
  v4f r = acc * sc;
  *((v4f*)(OUT + (size_t)row * F) + t) = r;
}

// ------------------------------------------------------ split-bf16 MFMA GEMM
__device__ inline void split8(const float* __restrict__ p, v8s& h8, v8s& l8) {
#pragma unroll
  for (int j = 0; j < 8; ++j) {
    float v = p[j];
    uint32_t u = __float_as_uint(v);
    uint32_t hb = (u + 0x7FFFu + ((u >> 16) & 1u)) >> 16;
    float hf = __uint_as_float(hb << 16);
    float lf = v - hf;
    uint32_t ul = __float_as_uint(lf);
    uint32_t lb = (ul + 0x7FFFu + ((ul >> 16) & 1u)) >> 16;
    h8[j] = (short)hb;
    l8[j] = (short)lb;
  }
}

// OUT[n,f] = act( X1[n,:]·W1[f,:] + X2[n,:]·W2[f,:] + bias[f] + addin[n,f] )
// A/B frag: row|col = lane&15, k = (lane>>4)*8+j.  C/D: col = lane&15,
// row = (lane>>4)*4 + reg  (verified gfx950 mappings).
template <int K1, int K2>
__global__ __launch_bounds__(256) void lin_kernel(
    const float* __restrict__ X1, const uint16_t* __restrict__ W1h, const uint16_t* __restrict__ W1l,
    const float* __restrict__ X2, const uint16_t* __restrict__ W2h, const uint16_t* __restrict__ W2l,
    const float* __restrict__ bias, const float* __restrict__ addin,
    float* __restrict__ OUT, int out_ld, int N, int F, int do_relu) {
  int wave = threadIdx.x >> 6;
  int lane = threadIdx.x & 63;
  int r = lane & 15, q = lane >> 4;
  int row0 = blockIdx.x * 64 + wave * 16;
  if (row0 >= N) return;

  constexpr int NK1 = K1 / 32;
  constexpr int NK2 = (K2 > 0) ? (K2 / 32) : 1;
  v8s a1h[NK1], a1l[NK1];
  v8s a2h[NK2], a2l[NK2];
#pragma unroll
  for (int kt = 0; kt < NK1; ++kt)
    split8(X1 + (size_t)(row0 + r) * K1 + kt * 32 + q * 8, a1h[kt], a1l[kt]);
  if constexpr (K2 > 0) {
#pragma unroll
    for (int kt = 0; kt < NK2; ++kt)
      split8(X2 + (size_t)(row0 + r) * K2 + kt * 32 + q * 8, a2h[kt], a2l[kt]);
  }

  int nf = (F + 15) >> 4;
  const v8s zz = {0, 0, 0, 0, 0, 0, 0, 0};
  for (int ft = 0; ft < nf; ++ft) {
    v4f acc = {0.f, 0.f, 0.f, 0.f};
    int wrow = ft * 16 + r;
    bool wv = wrow < F;
#pragma unroll
    for (int kt = 0; kt < NK1; ++kt) {
      v8s bh = wv ? *reinterpret_cast<const v8s*>(W1h + (size_t)wrow * K1 + kt * 32 + q * 8) : zz;
      v8s bl = wv ? *reinterpret_cast<const v8s*>(W1l + (size_t)wrow * K1 + kt * 32 + q * 8) : zz;
      acc = __builtin_amdgcn_mfma_f32_16x16x32_bf16(a1h[kt], bh, acc, 0, 0, 0);
      acc = __builtin_amdgcn_mfma_f32_16x16x32_bf16(a1l[kt], bh, acc, 0, 0, 0);
      acc = __builtin_amdgcn_mfma_f32_16x16x32_bf16(a1h[kt], bl, acc, 0, 0, 0);
    }
    if constexpr (K2 > 0) {
#pragma unroll
      for (int kt = 0; kt < NK2; ++kt) {
        v8s bh = wv ? *reinterpret_cast<const v8s*>(W2h + (size_t)wrow * K2 + kt * 32 + q * 8) : zz;
        v8s bl = wv ? *reinterpret_cast<const v8s*>(W2l + (size_t)wrow * K2 + kt * 32 + q * 8) : zz;
        acc = __builtin_amdgcn_mfma_f32_16x16x32_bf16(a2h[kt], bh, acc, 0, 0, 0);
        acc = __builtin_amdgcn_mfma_f32_16x16x32_bf16(a2l[kt], bh, acc, 0, 0, 0);
        acc = __builtin_amdgcn_mfma_f32_16x16x32_bf16(a2h[kt], bl, acc, 0, 0, 0);
      }
    }
    int col = ft * 16 + r;
    if (col < F) {
      float bv = bias ? bias[col] : 0.f;
#pragma unroll
      for (int i = 0; i < 4; ++i) {
        int row = row0 + q * 4 + i;
        if (row < N) {
          float v = acc[i] + bv;
          if (addin) v += addin[(size_t)row * F + col];
          if (do_relu) v = fmaxf(v, 0.f);
          OUT[(size_t)row * out_ld + col] = v;
        }
      }
    }
  }
}

// ------------------------------------------------------------- tiny epilogues
__global__ void hyper_bias_kernel(const float* __restrict__ S40,
                                  const float* __restrict__ b,
                                  float* __restrict__ XCAT) {
  int i = blockIdx.x * blockDim.x + threadIdx.x;
  if (i < N_NODES * 40) {
    int n = i / 40, c = i - n * 40;
    XCAT[(size_t)n * 80 + 40 + c] = S40[i] + b[c];
  }
}

__global__ __launch_bounds__(256) void final_ls_kernel(
    const float* __restrict__ XCAT, const float* __restrict__ lpw,
    const float* __restrict__ lpb, float* __restrict__ out) {
  int wid = (blockIdx.x * 256 + threadIdx.x) >> 6;
  int lane = threadIdx.x & 63;
  if (wid >= N_NODES) return;
  const float* xr = XCAT + (size_t)wid * 80;
  float logit = -1e30f;
  if (lane < 40) {
    float s = lpb[lane];
    const float* wr = lpw + lane * 80;
#pragma unroll 8
    for (int k = 0; k < 80; ++k) s += xr[k] * wr[k];
    logit = s;
  }
  float m = logit;
#pragma unroll
  for (int d = 1; d < 64; d <<= 1) m = fmaxf(m, __shfl_xor(m, d));
  float e = (lane < 40) ? __expf(logit - m) : 0.f;
  float ssum = e;
#pragma unroll
  for (int d = 1; d < 64; d <<= 1) ssum += __shfl_xor(ssum, d);
  if (lane < 40)
    out[(size_t)wid * 40 + lane] = logit - m - __logf(ssum);
}

// ---------------------------------------------------------------- launcher
extern "C" void kernel_launch(void* const* d_in, const int* in_sizes, int n_in,
                              void* d_out, int out_size, void* d_ws, size_t ws_size,
                              hipStream_t stream) {
  const float* x      = (const float*)d_in[0];
  const int* src      = (const int*)d_in[1];
  const int* dst      = (const int*)d_in[2];
  const int* he_node  = (const int*)d_in[3];
  const int* he_edge  = (const int*)d_in[4];
  const float* s0wl = (const float*)d_in[5],  *s0wr = (const float*)d_in[6],  *s0b = (const float*)d_in[7];
  const float* s1wl = (const float*)d_in[8],  *s1wr = (const float*)d_in[9],  *s1b = (const float*)d_in[10];
  const float* s2wl = (const float*)d_in[11], *s2wr = (const float*)d_in[12], *s2b = (const float*)d_in[13];
  const float* h0w = (const float*)d_in[14], *h0b = (const float*)d_in[15];
  const float* h1w = (const float*)d_in[16], *h1b = (const float*)d_in[17];
  const float* h2w = (const float*)d_in[18], *h2b = (const float*)d_in[19];
  const float* h3w = (const float*)d_in[20], *h3b = (const float*)d_in[21];
  const float* h4w = (const float*)d_in[22], *h4b = (const float*)d_in[23];
  const float* lpw = (const float*)d_in[24], *lpb = (const float*)d_in[25];
  float* out = (float*)d_out;

  char* p = (char*)d_ws;
  auto carve = [&](size_t bytes) -> char* {
    char* r = p;
    p += (bytes + 255) & ~(size_t)255;
    return r;
  };
  int* cnt_dst  = (int*)carve((size_t)N_NODES * 4);
  int* adj_off  = (int*)carve((size_t)(N_NODES + 1) * 4);
  int* adj_cur  = (int*)carve((size_t)N_NODES * 4);
  int* adj_src  = (int*)carve((size_t)N_EDGE * 4);
  int* cnt_he   = (int*)carve((size_t)N_HE * 4);
  int* heg_off  = (int*)carve((size_t)(N_HE + 1) * 4);
  int* heg_cur  = (int*)carve((size_t)N_HE * 4);
  int* heg_node = (int*)carve((size_t)N_INC * 4);
  int* cnt_hn   = (int*)carve((size_t)N_NODES * 4);
  int* hng_off  = (int*)carve((size_t)(N_NODES + 1) * 4);
  int* hng_cur  = (int*)carve((size_t)N_NODES * 4);
  int* hng_edge = (int*)carve((size_t)N_INC * 4);
  float* deg_inv = (float*)carve((size_t)N_NODES * 4);
  float* binv    = (float*)carve((size_t)N_HE * 4);
  float* dinv    = (float*)carve((size_t)N_NODES * 4);
  uint16_t* Wh = (uint16_t*)carve((size_t)W_TOTAL * 2);
  uint16_t* Wl = (uint16_t*)carve((size_t)W_TOTAL * 2);
  float* NA = (float*)carve((size_t)N_NODES * 256 * 4);   // 51.2 MB
  float* NB = (float*)carve((size_t)N_NODES * 256 * 4);
  float* NC = (float*)carve((size_t)N_NODES * 256 * 4);
  float* EF = (float*)carve((size_t)N_HE * 256 * 4);
  // aliases (lifetime-disjoint):
  float* U    = NC;                       // 50000x128, dead before NC written
  float* T40  = NA;                       // after NA (sage0 out) is dead
  float* S40  = NA + (size_t)N_NODES * 40;
  float* XCAT = NA + (size_t)N_NODES * 80;

  const int GE = (N_EDGE + 255) / 256;
  const int GN = (N_NODES + 255) / 256;
  const int GL = (N_NODES + 63) / 64;

  // ---- CSR build + weight split
  zero3_kernel<<<411, 256, 0, stream>>>(cnt_dst, N_NODES, cnt_he, N_HE, cnt_hn, N_NODES);
  hist_kernel<<<GE, 256, 0, stream>>>(dst, he_node, he_edge, cnt_dst, cnt_he, cnt_hn);
  scales_kernel<<<GN, 256, 0, stream>>>(cnt_dst, cnt_hn, cnt_he, deg_inv, dinv, binv);
  scan3_kernel<<<3, 1024, 0, stream>>>(cnt_dst, adj_off, adj_cur,
                                       cnt_he, heg_off, heg_cur,
                                       cnt_hn, hng_off, hng_cur);
  fill_kernel<<<GE, 256, 0, stream>>>(src, dst, he_node, he_edge,
                                      adj_cur, adj_src, heg_cur, heg_node,
                                      hng_cur, hng_edge);
  split_w_kernel<<<(W_TOTAL + 255) / 256, 256, 0, stream>>>(
      s0wl, s0wr, s1wl, s1wr, s2wl, s2wr, h0w, h1w, h2w, h3w, h4w, Wh, Wl);

  // ---- SAGE branch
  agg4_kernel<<<N_NODES, 64, 0, stream>>>(adj_off, adj_src, deg_inv, x, 128, U);
  lin_kernel<128, 128><<<GL, 256, 0, stream>>>(U, Wh + 0, Wl + 0, x, Wh + 32768, Wl + 32768,
                                               s0b, nullptr, NA, 256, N_NODES, 256, 1);
  agg4_kernel<<<N_NODES, 64, 0, stream>>>(adj_off, adj_src, deg_inv, NA, 256, NB);
  lin_kernel<256, 256><<<GL, 256, 0, stream>>>(NB, Wh + 65536, Wl + 65536, NA, Wh + 131072, Wl + 131072,
                                               s1b, nullptr, NC, 256, N_NODES, 256, 1);
  lin_kernel<256, 0><<<GL, 256, 0, stream>>>(NC, Wh + 196608, Wl + 196608, nullptr, nullptr, nullptr,
                                             nullptr, nullptr, T40, 40, N_NODES, 40, 0);
  agg4_kernel<<<N_NODES, 64, 0, stream>>>(adj_off, adj_src, deg_inv, T40, 40, S40);
  lin_kernel<256, 0><<<GL, 256, 0, stream>>>(NC, Wh + 206848, Wl + 206848, nullptr, nullptr, nullptr,
                                             s2b, S40, XCAT, 80, N_NODES, 40, 0);

  // ---- Hypergraph branch (ping-pong NC <-> NB via EF)
  agg4_kernel<<<N_HE, 64, 0, stream>>>(heg_off, heg_node, binv, x, 128, EF);
  agg4_kernel<<<N_NODES, 64, 0, stream>>>(hng_off, hng_edge, dinv, EF, 128, NB);
  lin_kernel<128, 0><<<GL, 256, 0, stream>>>(NB, Wh + 217088, Wl + 217088, nullptr, nullptr, nullptr,
                                             h0b, nullptr, NC, 256, N_NODES, 256, 1);
  agg4_kernel<<<N_HE, 64, 0, stream>>>(heg_off, heg_node, binv, NC, 256, EF);
  agg4_kernel<<<N_NODES, 64, 0, stream>>>(hng_off, hng_edge, dinv, EF, 256, NB);
  lin_kernel<256, 0><<<GL, 256, 0, stream>>>(NB, Wh + 249856, Wl + 249856, nullptr, nullptr, nullptr,
                                             h1b, nullptr, NC, 256, N_NODES, 256, 1);
  agg4_kernel<<<N_HE, 64, 0, stream>>>(heg_off, heg_node, binv, NC, 256, EF);
  agg4_kernel<<<N_NODES, 64, 0, stream>>>(hng_off, hng_edge, dinv, EF, 256, NB);
  lin_kernel<256, 0><<<GL, 256, 0, stream>>>(NB, Wh + 315392, Wl + 315392, nullptr, nullptr, nullptr,
                                             h2b, nullptr, NC, 256, N_NODES, 256, 1);
  agg4_kernel<<<N_HE, 64, 0, stream>>>(heg_off, heg_node, binv, NC, 256, EF);
  agg4_kernel<<<N_NODES, 64, 0, stream>>>(hng_off, hng_edge, dinv, EF, 256, NB);
  lin_kernel<256, 0><<<GL, 256, 0, stream>>>(NB, Wh + 380928, Wl + 380928, nullptr, nullptr, nullptr,
                                             h3b, nullptr, NC, 256, N_NODES, 256, 1);
  lin_kernel<256, 0><<<GL, 256, 0, stream>>>(NC, Wh + 446464, Wl + 446464, nullptr, nullptr, nullptr,
                                             nullptr, nullptr, T40, 40, N_NODES, 40, 0);
  agg4_kernel<<<N_HE, 64, 0, stream>>>(heg_off, heg_node, binv, T40, 40, EF);
  agg4_kernel<<<N_NODES, 64, 0, stream>>>(hng_off, hng_edge, dinv, EF, 40, S40);
  hyper_bias_kernel<<<(N_NODES * 40 + 255) / 256, 256, 0, stream>>>(S40, h4b, XCAT);

  // ---- final linear + log_softmax
  final_ls_kernel<<<(N_NODES + 3) / 4, 256, 0, stream>>>(XCAT, lpw, lpb, out);
}

// Round 4
// 1390.973 us; speedup vs baseline: 1.5612x; 1.5612x over previous
//
#include <hip/hip_runtime.h>
#include <hip/hip_bf16.h>
#include <cstdint>
#include <cstddef>

typedef __hip_bfloat16 bf16;
typedef short v8s __attribute__((ext_vector_type(8)));
typedef float v4f __attribute__((ext_vector_type(4)));

#define N_NODES 50000
#define N_HE    5000
#define N_EDGE  800000
#define N_INC   400000

// ---------------------------------------------------------------- CSR build
__global__ void zero3_kernel(int* a, int na, int* b, int nb, int* c, int nc) {
  int total = na + nb + nc;
  for (int i = blockIdx.x * blockDim.x + threadIdx.x; i < total;
       i += gridDim.x * blockDim.x) {
    if (i < na) a[i] = 0;
    else if (i < na + nb) b[i - na] = 0;
    else c[i - na - nb] = 0;
  }
}

__global__ void hist_kernel(const int* __restrict__ dst,
                            const int* __restrict__ he_node,
                            const int* __restrict__ he_edge,
                            int* cnt_dst, int* cnt_he, int* cnt_hn) {
  int i = blockIdx.x * blockDim.x + threadIdx.x;
  if (i < N_EDGE) atomicAdd(&cnt_dst[dst[i]], 1);
  if (i < N_INC) {
    atomicAdd(&cnt_he[he_edge[i]], 1);
    atomicAdd(&cnt_hn[he_node[i]], 1);
  }
}

__global__ void scales_kernel(const int* cnt_dst, const int* cnt_hn,
                              const int* cnt_he,
                              float* deg_inv, float* dinv, float* binv) {
  int i = blockIdx.x * blockDim.x + threadIdx.x;
  if (i < N_NODES) {
    int d = cnt_dst[i];
    deg_inv[i] = 1.0f / (float)(d > 1 ? d : 1);
    int h = cnt_hn[i];
    dinv[i] = h > 0 ? 1.0f / (float)h : 0.0f;
  }
  if (i < N_HE) {
    int e = cnt_he[i];
    binv[i] = e > 0 ? 1.0f / (float)e : 0.0f;
  }
}

__global__ void scan3_kernel(const int* cnt_dst, int* adj_off, int* adj_cur,
                             const int* cnt_he, int* heg_off, int* heg_cur,
                             const int* cnt_hn, int* hng_off, int* hng_cur) {
  const int* cnt; int* off; int* cur; int n;
  if (blockIdx.x == 0)      { cnt = cnt_dst; off = adj_off; cur = adj_cur; n = N_NODES; }
  else if (blockIdx.x == 1) { cnt = cnt_he;  off = heg_off; cur = heg_cur; n = N_HE; }
  else                      { cnt = cnt_hn;  off = hng_off; cur = hng_cur; n = N_NODES; }
  __shared__ int buf[1024];
  int t = threadIdx.x;
  int carry = 0;
  for (int base = 0; base < n; base += 1024) {
    int i = base + t;
    int v = (i < n) ? cnt[i] : 0;
    buf[t] = v;
    __syncthreads();
    for (int d = 1; d < 1024; d <<= 1) {
      int x = (t >= d) ? buf[t - d] : 0;
      __syncthreads();
      buf[t] += x;
      __syncthreads();
    }
    int excl = buf[t] - v;
    if (i < n) { off[i] = carry + excl; cur[i] = carry + excl; }
    int total = buf[1023];
    __syncthreads();
    carry += total;
  }
  if (t == 0) off[n] = carry;
}

__global__ void fill_kernel(const int* __restrict__ src, const int* __restrict__ dst,
                            const int* __restrict__ he_node, const int* __restrict__ he_edge,
                            int* adj_cur, int* adj_src,
                            int* heg_cur, int* heg_node,
                            int* hng_cur, int* hng_edge) {
  int i = blockIdx.x * blockDim.x + threadIdx.x;
  if (i < N_EDGE) {
    int p = atomicAdd(&adj_cur[dst[i]], 1);
    adj_src[p] = src[i];
  }
  if (i < N_INC) {
    int p = atomicAdd(&heg_cur[he_edge[i]], 1);
    heg_node[p] = he_node[i];
    int p2 = atomicAdd(&hng_cur[he_node[i]], 1);
    hng_edge[p2] = he_edge[i];
  }
}

// ---------------------------------------------------- weight hi/lo bf16 split
#define W_TOTAL 456704
__global__ void split_w_kernel(const float* s0wl, const float* s0wr,
                               const float* s1wl, const float* s1wr,
                               const float* s2wl, const float* s2wr,
                               const float* h0w, const float* h1w,
                               const float* h2w, const float* h3w,
                               const float* h4w,
                               uint16_t* hi, uint16_t* lo) {
  int i = blockIdx.x * blockDim.x + threadIdx.x;
  if (i >= W_TOTAL) return;
  const float* src; int base;
  if (i < 32768)       { src = s0wl; base = 0; }
  else if (i < 65536)  { src = s0wr; base = 32768; }
  else if (i < 131072) { src = s1wl; base = 65536; }
  else if (i < 196608) { src = s1wr; base = 131072; }
  else if (i < 206848) { src = s2wl; base = 196608; }
  else if (i < 217088) { src = s2wr; base = 206848; }
  else if (i < 249856) { src = h0w;  base = 217088; }
  else if (i < 315392) { src = h1w;  base = 249856; }
  else if (i < 380928) { src = h2w;  base = 315392; }
  else if (i < 446464) { src = h3w;  base = 380928; }
  else                 { src = h4w;  base = 446464; }
  float v = src[i - base];
  uint32_t u = __float_as_uint(v);
  uint32_t hb = (u + 0x7FFFu + ((u >> 16) & 1u)) >> 16;
  float hf = __uint_as_float(hb << 16);
  float lf = v - hf;
  uint32_t ul = __float_as_uint(lf);
  uint32_t lb = (ul + 0x7FFFu + ((ul >> 16) & 1u)) >> 16;
  hi[i] = (uint16_t)hb;
  lo[i] = (uint16_t)lb;
}

// ------------------------------------------------- CSR gather-mean, float4
__global__ void agg4_kernel(const int* __restrict__ off, const int* __restrict__ idx,
                            const float* __restrict__ scale,
                            const float* __restrict__ X, int F,
                            float* __restrict__ OUT) {
  int row = blockIdx.x;
  int t = threadIdx.x;
  int F4 = F >> 2;
  if (t >= F4) return;
  int j0 = off[row], j1 = off[row + 1];
  float sc = scale[row];
  v4f acc = {0.f, 0.f, 0.f, 0.f};
  for (int j = j0; j < j1; ++j) {
    int s = idx[j];
    v4f v = *((const v4f*)(X + (size_t)s * F) + t);
    acc += v;
  }
  v4f r = acc * sc;
  *((v4f*)(OUT + (size_t)row * F) + t) = r;
}

// ------------------------------------------------------ split-bf16 MFMA GEMM
__device__ inline void split8(const float* __restrict__ p, v8s& h8, v8s& l8) {
#pragma unroll
  for (int j = 0; j < 8; ++j) {
    float v = p[j];
    uint32_t u = __float_as_uint(v);
    uint32_t hb = (u + 0x7FFFu + ((u >> 16) & 1u)) >> 16;
    float hf = __uint_as_float(hb << 16);
    float lf = v - hf;
    uint32_t ul = __float_as_uint(lf);
    uint32_t lb = (ul + 0x7FFFu + ((ul >> 16) & 1u)) >> 16;
    h8[j] = (short)hb;
    l8[j] = (short)lb;
  }
}

// LDS-staged split-bf16 GEMM.
// OUT[n,f] = act( X1[n,:]·W1[f,:] (+ X2[n,:]·W2[f,:]) + bias[f] + addin[n,f] )
// K-chunks of 32; W chunk (hi+lo) staged to LDS (row stride 40 shorts ->
// 2-way bank aliasing only, free per m136). 4 blocks/CU (LDS 40KB, VGPR<=128).
// A/B frag: row|col = lane&15, k = (lane>>4)*8+j.  C/D: col = lane&15,
// row = (lane>>4)*4 + reg  (verified gfx950 mappings).
template <int K1, int K2, int F>
__global__ __launch_bounds__(256, 4) void lin2_kernel(
    const float* __restrict__ X1, const uint16_t* __restrict__ W1h, const uint16_t* __restrict__ W1l,
    const float* __restrict__ X2, const uint16_t* __restrict__ W2h, const uint16_t* __restrict__ W2l,
    const float* __restrict__ bias, const float* __restrict__ addin,
    float* __restrict__ OUT, int out_ld, int N, int do_relu) {
  constexpr int FP  = (F + 15) & ~15;     // padded row count
  constexpr int NF  = FP / 16;            // 16x16 C tiles per wave
  constexpr int NC1 = K1 / 32;
  constexpr int NCH = (K1 + (K2 > 0 ? K2 : 0)) / 32;
  constexpr int RS  = 40;                 // LDS row stride (shorts): 32 + 8 pad
  __shared__ short sW[2][FP][RS];

  int tid  = threadIdx.x;
  int wave = tid >> 6, lane = tid & 63;
  int r = lane & 15, q = lane >> 4;
  int row0 = blockIdx.x * 64 + wave * 16;
  int rowA = row0 + r; if (rowA > N - 1) rowA = N - 1;   // clamp OOB loads

  int srow = tid >> 2;        // 0..63 staging row within pass
  int sj   = tid & 3;         // 16B sub-chunk

  v4f acc[NF];
#pragma unroll
  for (int i = 0; i < NF; ++i) acc[i] = (v4f){0.f, 0.f, 0.f, 0.f};

  for (int c = 0; c < NCH; ++c) {
    const bool first = (K2 == 0) || (c < NC1);
    const uint16_t* Wh = first ? W1h : W2h;
    const uint16_t* Wl = first ? W1l : W2l;
    const float*    Xs = first ? X1 : X2;
    const int K  = first ? K1 : K2;
    const int kc = (first ? c : c - NC1) * 32;

    if (c) __syncthreads();   // previous chunk fully consumed before overwrite
    const v8s zz = {0, 0, 0, 0, 0, 0, 0, 0};
#pragma unroll
    for (int pass = 0; pass < (FP + 63) / 64; ++pass) {
      int row = srow + pass * 64;
      if (row < FP) {
        v8s hv = zz, lv = zz;
        if (row < F) {
          hv = *reinterpret_cast<const v8s*>(Wh + (size_t)row * K + kc + sj * 8);
          lv = *reinterpret_cast<const v8s*>(Wl + (size_t)row * K + kc + sj * 8);
        }
        *reinterpret_cast<v8s*>(&sW[0][row][sj * 8]) = hv;
        *reinterpret_cast<v8s*>(&sW[1][row][sj * 8]) = lv;
      }
    }
    v8s ah, al;
    split8(Xs + (size_t)rowA * K + kc + q * 8, ah, al);
    __syncthreads();
#pragma unroll
    for (int ft = 0; ft < NF; ++ft) {
      v8s bh = *reinterpret_cast<const v8s*>(&sW[0][ft * 16 + r][q * 8]);
      v8s bl = *reinterpret_cast<const v8s*>(&sW[1][ft * 16 + r][q * 8]);
      acc[ft] = __builtin_amdgcn_mfma_f32_16x16x32_bf16(ah, bh, acc[ft], 0, 0, 0);
      acc[ft] = __builtin_amdgcn_mfma_f32_16x16x32_bf16(al, bh, acc[ft], 0, 0, 0);
      acc[ft] = __builtin_amdgcn_mfma_f32_16x16x32_bf16(ah, bl, acc[ft], 0, 0, 0);
    }
  }

#pragma unroll
  for (int ft = 0; ft < NF; ++ft) {
    int col = ft * 16 + r;
    if (col < F) {
      float bv = bias ? bias[col] : 0.f;
#pragma unroll
      for (int i = 0; i < 4; ++i) {
        int row = row0 + q * 4 + i;
        if (row < N) {
          float v = acc[ft][i] + bv;
          if (addin) v += addin[(size_t)row * F + col];
          if (do_relu) v = fmaxf(v, 0.f);
          OUT[(size_t)row * out_ld + col] = v;
        }
      }
    }
  }
}

// ------------------------------------------------------------- tiny epilogues
__global__ void hyper_bias_kernel(const float* __restrict__ S40,
                                  const float* __restrict__ b,
                                  float* __restrict__ XCAT) {
  int i = blockIdx.x * blockDim.x + threadIdx.x;
  if (i < N_NODES * 40) {
    int n = i / 40, c = i - n * 40;
    XCAT[(size_t)n * 80 + 40 + c] = S40[i] + b[c];
  }
}

__global__ __launch_bounds__(256) void final_ls_kernel(
    const float* __restrict__ XCAT, const float* __restrict__ lpw,
    const float* __restrict__ lpb, float* __restrict__ out) {
  int wid = (blockIdx.x * 256 + threadIdx.x) >> 6;
  int lane = threadIdx.x & 63;
  if (wid >= N_NODES) return;
  const float* xr = XCAT + (size_t)wid * 80;
  float logit = -1e30f;
  if (lane < 40) {
    float s = lpb[lane];
    const float* wr = lpw + lane * 80;
#pragma unroll 8
    for (int k = 0; k < 80; ++k) s += xr[k] * wr[k];
    logit = s;
  }
  float m = logit;
#pragma unroll
  for (int d = 1; d < 64; d <<= 1) m = fmaxf(m, __shfl_xor(m, d));
  float e = (lane < 40) ? __expf(logit - m) : 0.f;
  float ssum = e;
#pragma unroll
  for (int d = 1; d < 64; d <<= 1) ssum += __shfl_xor(ssum, d);
  if (lane < 40)
    out[(size_t)wid * 40 + lane] = logit - m - __logf(ssum);
}

// ---------------------------------------------------------------- launcher
extern "C" void kernel_launch(void* const* d_in, const int* in_sizes, int n_in,
                              void* d_out, int out_size, void* d_ws, size_t ws_size,
                              hipStream_t stream) {
  const float* x      = (const float*)d_in[0];
  const int* src      = (const int*)d_in[1];
  const int* dst      = (const int*)d_in[2];
  const int* he_node  = (const int*)d_in[3];
  const int* he_edge  = (const int*)d_in[4];
  const float* s0wl = (const float*)d_in[5],  *s0wr = (const float*)d_in[6],  *s0b = (const float*)d_in[7];
  const float* s1wl = (const float*)d_in[8],  *s1wr = (const float*)d_in[9],  *s1b = (const float*)d_in[10];
  const float* s2wl = (const float*)d_in[11], *s2wr = (const float*)d_in[12], *s2b = (const float*)d_in[13];
  const float* h0w = (const float*)d_in[14], *h0b = (const float*)d_in[15];
  const float* h1w = (const float*)d_in[16], *h1b = (const float*)d_in[17];
  const float* h2w = (const float*)d_in[18], *h2b = (const float*)d_in[19];
  const float* h3w = (const float*)d_in[20], *h3b = (const float*)d_in[21];
  const float* h4w = (const float*)d_in[22], *h4b = (const float*)d_in[23];
  const float* lpw = (const float*)d_in[24], *lpb = (const float*)d_in[25];
  float* out = (float*)d_out;

  char* p = (char*)d_ws;
  auto carve = [&](size_t bytes) -> char* {
    char* r = p;
    p += (bytes + 255) & ~(size_t)255;
    return r;
  };
  int* cnt_dst  = (int*)carve((size_t)N_NODES * 4);
  int* adj_off  = (int*)carve((size_t)(N_NODES + 1) * 4);
  int* adj_cur  = (int*)carve((size_t)N_NODES * 4);
  int* adj_src  = (int*)carve((size_t)N_EDGE * 4);
  int* cnt_he   = (int*)carve((size_t)N_HE * 4);
  int* heg_off  = (int*)carve((size_t)(N_HE + 1) * 4);
  int* heg_cur  = (int*)carve((size_t)N_HE * 4);
  int* heg_node = (int*)carve((size_t)N_INC * 4);
  int* cnt_hn   = (int*)carve((size_t)N_NODES * 4);
  int* hng_off  = (int*)carve((size_t)(N_NODES + 1) * 4);
  int* hng_cur  = (int*)carve((size_t)N_NODES * 4);
  int* hng_edge = (int*)carve((size_t)N_INC * 4);
  float* deg_inv = (float*)carve((size_t)N_NODES * 4);
  float* binv    = (float*)carve((size_t)N_HE * 4);
  float* dinv    = (float*)carve((size_t)N_NODES * 4);
  uint16_t* Wh = (uint16_t*)carve((size_t)W_TOTAL * 2);
  uint16_t* Wl = (uint16_t*)carve((size_t)W_TOTAL * 2);
  float* NA = (float*)carve((size_t)N_NODES * 256 * 4);
  float* NB = (float*)carve((size_t)N_NODES * 256 * 4);
  float* NC = (float*)carve((size_t)N_NODES * 256 * 4);
  float* EF = (float*)carve((size_t)N_HE * 256 * 4);
  // aliases (lifetime-disjoint):
  float* U    = NC;                       // 50000x128, dead before NC written
  float* T40  = NA;                       // after NA (sage0 out) is dead
  float* S40  = NA + (size_t)N_NODES * 40;
  float* XCAT = NA + (size_t)N_NODES * 80;

  const int GE = (N_EDGE + 255) / 256;
  const int GN = (N_NODES + 255) / 256;
  const int GL = (N_NODES + 63) / 64;

  // ---- CSR build + weight split
  zero3_kernel<<<411, 256, 0, stream>>>(cnt_dst, N_NODES, cnt_he, N_HE, cnt_hn, N_NODES);
  hist_kernel<<<GE, 256, 0, stream>>>(dst, he_node, he_edge, cnt_dst, cnt_he, cnt_hn);
  scales_kernel<<<GN, 256, 0, stream>>>(cnt_dst, cnt_hn, cnt_he, deg_inv, dinv, binv);
  scan3_kernel<<<3, 1024, 0, stream>>>(cnt_dst, adj_off, adj_cur,
                                       cnt_he, heg_off, heg_cur,
                                       cnt_hn, hng_off, hng_cur);
  fill_kernel<<<GE, 256, 0, stream>>>(src, dst, he_node, he_edge,
                                      adj_cur, adj_src, heg_cur, heg_node,
                                      hng_cur, hng_edge);
  split_w_kernel<<<(W_TOTAL + 255) / 256, 256, 0, stream>>>(
      s0wl, s0wr, s1wl, s1wr, s2wl, s2wr, h0w, h1w, h2w, h3w, h4w, Wh, Wl);

  // ---- SAGE branch
  agg4_kernel<<<N_NODES, 64, 0, stream>>>(adj_off, adj_src, deg_inv, x, 128, U);
  lin2_kernel<128, 128, 256><<<GL, 256, 0, stream>>>(
      U, Wh + 0, Wl + 0, x, Wh + 32768, Wl + 32768, s0b, nullptr, NA, 256, N_NODES, 1);
  agg4_kernel<<<N_NODES, 64, 0, stream>>>(adj_off, adj_src, deg_inv, NA, 256, NB);
  lin2_kernel<256, 256, 256><<<GL, 256, 0, stream>>>(
      NB, Wh + 65536, Wl + 65536, NA, Wh + 131072, Wl + 131072, s1b, nullptr, NC, 256, N_NODES, 1);
  lin2_kernel<256, 0, 40><<<GL, 256, 0, stream>>>(
      NC, Wh + 196608, Wl + 196608, nullptr, nullptr, nullptr, nullptr, nullptr, T40, 40, N_NODES, 0);
  agg4_kernel<<<N_NODES, 64, 0, stream>>>(adj_off, adj_src, deg_inv, T40, 40, S40);
  lin2_kernel<256, 0, 40><<<GL, 256, 0, stream>>>(
      NC, Wh + 206848, Wl + 206848, nullptr, nullptr, nullptr, s2b, S40, XCAT, 80, N_NODES, 0);

  // ---- Hypergraph branch (g lives in NC; per layer: NC->EF->NB->NC)
  agg4_kernel<<<N_HE, 64, 0, stream>>>(heg_off, heg_node, binv, x, 128, EF);
  agg4_kernel<<<N_NODES, 64, 0, stream>>>(hng_off, hng_edge, dinv, EF, 128, NB);
  lin2_kernel<128, 0, 256><<<GL, 256, 0, stream>>>(
      NB, Wh + 217088, Wl + 217088, nullptr, nullptr, nullptr, h0b, nullptr, NC, 256, N_NODES, 1);
  agg4_kernel<<<N_HE, 64, 0, stream>>>(heg_off, heg_node, binv, NC, 256, EF);
  agg4_kernel<<<N_NODES, 64, 0, stream>>>(hng_off, hng_edge, dinv, EF, 256, NB);
  lin2_kernel<256, 0, 256><<<GL, 256, 0, stream>>>(
      NB, Wh + 249856, Wl + 249856, nullptr, nullptr, nullptr, h1b, nullptr, NC, 256, N_NODES, 1);
  agg4_kernel<<<N_HE, 64, 0, stream>>>(heg_off, heg_node, binv, NC, 256, EF);
  agg4_kernel<<<N_NODES, 64, 0, stream>>>(hng_off, hng_edge, dinv, EF, 256, NB);
  lin2_kernel<256, 0, 256><<<GL, 256, 0, stream>>>(
      NB, Wh + 315392, Wl + 315392, nullptr, nullptr, nullptr, h2b, nullptr, NC, 256, N_NODES, 1);
  agg4_kernel<<<N_HE, 64, 0, stream>>>(heg_off, heg_node, binv, NC, 256, EF);
  agg4_kernel<<<N_NODES, 64, 0, stream>>>(hng_off, hng_edge, dinv, EF, 256, NB);
  lin2_kernel<256, 0, 256><<<GL, 256, 0, stream>>>(
      NB, Wh + 380928, Wl + 380928, nullptr, nullptr, nullptr, h3b, nullptr, NC, 256, N_NODES, 1);
  lin2_kernel<256, 0, 40><<<GL, 256, 0, stream>>>(
      NC, Wh + 446464, Wl + 446464, nullptr, nullptr, nullptr, nullptr, nullptr, T40, 40, N_NODES, 0);
  agg4_kernel<<<N_HE, 64, 0, stream>>>(heg_off, heg_node, binv, T40, 40, EF);
  agg4_kernel<<<N_NODES, 64, 0, stream>>>(hng_off, hng_edge, dinv, EF, 40, S40);
  hyper_bias_kernel<<<(N_NODES * 40 + 255) / 256, 256, 0, stream>>>(S40, h4b, XCAT);

  // ---- final linear + log_softmax
  final_ls_kernel<<<(N_NODES + 3) / 4, 256, 0, stream>>>(XCAT, lpw, lpb, out);
}

// Round 5
// 1062.988 us; speedup vs baseline: 2.0429x; 1.3086x over previous
//
#include <hip/hip_runtime.h>
#include <hip/hip_bf16.h>
#include <cstdint>
#include <cstddef>

typedef __hip_bfloat16 bf16;
typedef short v8s __attribute__((ext_vector_type(8)));
typedef float v4f __attribute__((ext_vector_type(4)));
typedef unsigned short v4u __attribute__((ext_vector_type(4)));
typedef unsigned short v2u __attribute__((ext_vector_type(2)));

#define N_NODES 50000
#define N_HE    5000
#define N_EDGE  800000
#define N_INC   400000

__device__ inline float bfh(uint32_t u) { return __uint_as_float(u << 16); }
__device__ inline uint16_t rne16(float f) {
  uint32_t u = __float_as_uint(f);
  return (uint16_t)((u + 0x7FFFu + ((u >> 16) & 1u)) >> 16);
}

// ---------------------------------------------------------------- CSR build
__global__ void zero3_kernel(int* a, int na, int* b, int nb, int* c, int nc) {
  int total = na + nb + nc;
  for (int i = blockIdx.x * blockDim.x + threadIdx.x; i < total;
       i += gridDim.x * blockDim.x) {
    if (i < na) a[i] = 0;
    else if (i < na + nb) b[i - na] = 0;
    else c[i - na - nb] = 0;
  }
}

__global__ void hist_kernel(const int* __restrict__ dst,
                            const int* __restrict__ he_node,
                            const int* __restrict__ he_edge,
                            int* cnt_dst, int* cnt_he, int* cnt_hn) {
  int i = blockIdx.x * blockDim.x + threadIdx.x;
  if (i < N_EDGE) atomicAdd(&cnt_dst[dst[i]], 1);
  if (i < N_INC) {
    atomicAdd(&cnt_he[he_edge[i]], 1);
    atomicAdd(&cnt_hn[he_node[i]], 1);
  }
}

__global__ void scales_kernel(const int* cnt_dst, const int* cnt_hn,
                              const int* cnt_he,
                              float* deg_inv, float* dinv, float* binv) {
  int i = blockIdx.x * blockDim.x + threadIdx.x;
  if (i < N_NODES) {
    int d = cnt_dst[i];
    deg_inv[i] = 1.0f / (float)(d > 1 ? d : 1);
    int h = cnt_hn[i];
    dinv[i] = h > 0 ? 1.0f / (float)h : 0.0f;
  }
  if (i < N_HE) {
    int e = cnt_he[i];
    binv[i] = e > 0 ? 1.0f / (float)e : 0.0f;
  }
}

__global__ void scan3_kernel(const int* cnt_dst, int* adj_off, int* adj_cur,
                             const int* cnt_he, int* heg_off, int* heg_cur,
                             const int* cnt_hn, int* hng_off, int* hng_cur) {
  const int* cnt; int* off; int* cur; int n;
  if (blockIdx.x == 0)      { cnt = cnt_dst; off = adj_off; cur = adj_cur; n = N_NODES; }
  else if (blockIdx.x == 1) { cnt = cnt_he;  off = heg_off; cur = heg_cur; n = N_HE; }
  else                      { cnt = cnt_hn;  off = hng_off; cur = hng_cur; n = N_NODES; }
  __shared__ int buf[1024];
  int t = threadIdx.x;
  int carry = 0;
  for (int base = 0; base < n; base += 1024) {
    int i = base + t;
    int v = (i < n) ? cnt[i] : 0;
    buf[t] = v;
    __syncthreads();
    for (int d = 1; d < 1024; d <<= 1) {
      int x = (t >= d) ? buf[t - d] : 0;
      __syncthreads();
      buf[t] += x;
      __syncthreads();
    }
    int excl = buf[t] - v;
    if (i < n) { off[i] = carry + excl; cur[i] = carry + excl; }
    int total = buf[1023];
    __syncthreads();
    carry += total;
  }
  if (t == 0) off[n] = carry;
}

__global__ void fill_kernel(const int* __restrict__ src, const int* __restrict__ dst,
                            const int* __restrict__ he_node, const int* __restrict__ he_edge,
                            int* adj_cur, int* adj_src,
                            int* heg_cur, int* heg_node,
                            int* hng_cur, int* hng_edge) {
  int i = blockIdx.x * blockDim.x + threadIdx.x;
  if (i < N_EDGE) {
    int p = atomicAdd(&adj_cur[dst[i]], 1);
    adj_src[p] = src[i];
  }
  if (i < N_INC) {
    int p = atomicAdd(&heg_cur[he_edge[i]], 1);
    heg_node[p] = he_node[i];
    int p2 = atomicAdd(&hng_cur[he_node[i]], 1);
    hng_edge[p2] = he_edge[i];
  }
}

// ---------------------------------------------------- weight hi/lo bf16 split
#define W_TOTAL 456704
__global__ void split_w_kernel(const float* s0wl, const float* s0wr,
                               const float* s1wl, const float* s1wr,
                               const float* s2wl, const float* s2wr,
                               const float* h0w, const float* h1w,
                               const float* h2w, const float* h3w,
                               const float* h4w,
                               uint16_t* hi, uint16_t* lo) {
  int i = blockIdx.x * blockDim.x + threadIdx.x;
  if (i >= W_TOTAL) return;
  const float* src; int base;
  if (i < 32768)       { src = s0wl; base = 0; }
  else if (i < 65536)  { src = s0wr; base = 32768; }
  else if (i < 131072) { src = s1wl; base = 65536; }
  else if (i < 196608) { src = s1wr; base = 131072; }
  else if (i < 206848) { src = s2wl; base = 196608; }
  else if (i < 217088) { src = s2wr; base = 206848; }
  else if (i < 249856) { src = h0w;  base = 217088; }
  else if (i < 315392) { src = h1w;  base = 249856; }
  else if (i < 380928) { src = h2w;  base = 315392; }
  else if (i < 446464) { src = h3w;  base = 380928; }
  else                 { src = h4w;  base = 446464; }
  float v = src[i - base];
  uint16_t hb = rne16(v);
  float lf = v - bfh(hb);
  hi[i] = hb;
  lo[i] = rne16(lf);
}

// ---------------------------------------------------------- x f32 -> bf16
__global__ void cvt_kernel(const float* __restrict__ X, uint16_t* __restrict__ O, int n4) {
  int i = blockIdx.x * blockDim.x + threadIdx.x;
  if (i >= n4) return;
  v4f v = *((const v4f*)X + i);
  v4u o;
  o[0] = rne16(v[0]); o[1] = rne16(v[1]); o[2] = rne16(v[2]); o[3] = rne16(v[3]);
  *((v4u*)O + i) = o;
}

// ------------------------------------------- CSR gather-mean over bf16 rows
// OUT[row,:] = rne16( scale[row] * sum_j X[idx[j],:] ).  64-thread blocks.
// F=256: lane owns 4 cols (8B); F<=128: 2 cols (4B). Neighbor loop unrolled x4.
template <int F>
__global__ void aggb_kernel(const int* __restrict__ off, const int* __restrict__ idx,
                            const float* __restrict__ scale,
                            const uint16_t* __restrict__ X,
                            uint16_t* __restrict__ OUT) {
  constexpr int VEC = (F >= 256) ? 4 : 2;
  int row = blockIdx.x;
  int t = threadIdx.x;
  if (t * VEC >= F) return;
  int j0 = off[row], j1 = off[row + 1];
  float sc = scale[row];
  float acc[VEC];
#pragma unroll
  for (int k = 0; k < VEC; ++k) acc[k] = 0.f;

  int j = j0;
  for (; j + 3 < j1; j += 4) {
    int s0 = idx[j], s1 = idx[j + 1], s2 = idx[j + 2], s3 = idx[j + 3];
    if (VEC == 4) {
      v4u a = *(const v4u*)(X + (size_t)s0 * F + t * 4);
      v4u b = *(const v4u*)(X + (size_t)s1 * F + t * 4);
      v4u c = *(const v4u*)(X + (size_t)s2 * F + t * 4);
      v4u d = *(const v4u*)(X + (size_t)s3 * F + t * 4);
#pragma unroll
      for (int k = 0; k < 4; ++k)
        acc[k] += bfh(a[k]) + bfh(b[k]) + bfh(c[k]) + bfh(d[k]);
    } else {
      v2u a = *(const v2u*)(X + (size_t)s0 * F + t * 2);
      v2u b = *(const v2u*)(X + (size_t)s1 * F + t * 2);
      v2u c = *(const v2u*)(X + (size_t)s2 * F + t * 2);
      v2u d = *(const v2u*)(X + (size_t)s3 * F + t * 2);
#pragma unroll
      for (int k = 0; k < 2; ++k)
        acc[k] += bfh(a[k]) + bfh(b[k]) + bfh(c[k]) + bfh(d[k]);
    }
  }
  for (; j < j1; ++j) {
    int s = idx[j];
    if (VEC == 4) {
      v4u a = *(const v4u*)(X + (size_t)s * F + t * 4);
#pragma unroll
      for (int k = 0; k < 4; ++k) acc[k] += bfh(a[k]);
    } else {
      v2u a = *(const v2u*)(X + (size_t)s * F + t * 2);
#pragma unroll
      for (int k = 0; k < 2; ++k) acc[k] += bfh(a[k]);
    }
  }

  if (VEC == 4) {
    v4u o;
#pragma unroll
    for (int k = 0; k < 4; ++k) o[k] = rne16(acc[k] * sc);
    *(v4u*)(OUT + (size_t)row * F + t * 4) = o;
  } else {
    v2u o;
#pragma unroll
    for (int k = 0; k < 2; ++k) o[k] = rne16(acc[k] * sc);
    *(v2u*)(OUT + (size_t)row * F + t * 2) = o;
  }
}

// Final hyper agg (F=40) fused with bias, f32 out into XCAT[:,40:].
__global__ void agg40b_kernel(const int* __restrict__ off, const int* __restrict__ idx,
                              const float* __restrict__ scale,
                              const uint16_t* __restrict__ EF40,
                              const float* __restrict__ bias,
                              float* __restrict__ XCAT) {
  int row = blockIdx.x;
  int t = threadIdx.x;
  if (t >= 20) return;
  int j0 = off[row], j1 = off[row + 1];
  float sc = scale[row];
  float a0 = 0.f, a1 = 0.f;
  for (int j = j0; j < j1; ++j) {
    int s = idx[j];
    v2u v = *(const v2u*)(EF40 + (size_t)s * 40 + t * 2);
    a0 += bfh(v[0]);
    a1 += bfh(v[1]);
  }
  XCAT[(size_t)row * 80 + 40 + t * 2]     = a0 * sc + bias[t * 2];
  XCAT[(size_t)row * 80 + 40 + t * 2 + 1] = a1 * sc + bias[t * 2 + 1];
}

// ------------------------------------- bf16-A, split-W LDS-staged MFMA GEMM
// OUT[n,f] = act( X1[n,:]·W1[f,:] (+ X2[n,:]·W2[f,:]) + bias[f] + addin[n,f] )
// A exact bf16 from memory; W = Wh + Wl (hi/lo bf16 split, f32-accurate).
// A/B frag: row|col = lane&15, k = (lane>>4)*8+j.  C/D: col = lane&15,
// row = (lane>>4)*4 + reg  (verified gfx950 mappings).
template <int K1, int K2, int F, bool OUTBF>
__global__ __launch_bounds__(256, 4) void lin2b_kernel(
    const uint16_t* __restrict__ X1, const uint16_t* __restrict__ W1h, const uint16_t* __restrict__ W1l,
    const uint16_t* __restrict__ X2, const uint16_t* __restrict__ W2h, const uint16_t* __restrict__ W2l,
    const float* __restrict__ bias, const uint16_t* __restrict__ addin,
    void* __restrict__ OUTP, int out_ld, int N, int do_relu) {
  constexpr int FP  = (F + 15) & ~15;
  constexpr int NF  = FP / 16;
  constexpr int NC1 = K1 / 32;
  constexpr int NCH = (K1 + (K2 > 0 ? K2 : 0)) / 32;
  constexpr int RS  = 40;                 // LDS row stride (shorts): 2-way alias only
  __shared__ short sW[2][FP][RS];

  int tid  = threadIdx.x;
  int wave = tid >> 6, lane = tid & 63;
  int r = lane & 15, q = lane >> 4;
  int row0 = blockIdx.x * 64 + wave * 16;
  int rowA = row0 + r; if (rowA > N - 1) rowA = N - 1;

  int srow = tid >> 2;
  int sj   = tid & 3;

  v4f acc[NF];
#pragma unroll
  for (int i = 0; i < NF; ++i) acc[i] = (v4f){0.f, 0.f, 0.f, 0.f};

  for (int c = 0; c < NCH; ++c) {
    const bool first = (K2 == 0) || (c < NC1);
    const uint16_t* Wh = first ? W1h : W2h;
    const uint16_t* Wl = first ? W1l : W2l;
    const uint16_t* Xs = first ? X1 : X2;
    const int K  = first ? K1 : K2;
    const int kc = (first ? c : c - NC1) * 32;

    if (c) __syncthreads();
    const v8s zz = {0, 0, 0, 0, 0, 0, 0, 0};
#pragma unroll
    for (int pass = 0; pass < (FP + 63) / 64; ++pass) {
      int row = srow + pass * 64;
      if (row < FP) {
        v8s hv = zz, lv = zz;
        if (row < F) {
          hv = *reinterpret_cast<const v8s*>(Wh + (size_t)row * K + kc + sj * 8);
          lv = *reinterpret_cast<const v8s*>(Wl + (size_t)row * K + kc + sj * 8);
        }
        *reinterpret_cast<v8s*>(&sW[0][row][sj * 8]) = hv;
        *reinterpret_cast<v8s*>(&sW[1][row][sj * 8]) = lv;
      }
    }
    v8s ah = *reinterpret_cast<const v8s*>(Xs + (size_t)rowA * K + kc + q * 8);
    __syncthreads();
#pragma unroll
    for (int ft = 0; ft < NF; ++ft) {
      v8s bh = *reinterpret_cast<const v8s*>(&sW[0][ft * 16 + r][q * 8]);
      v8s bl = *reinterpret_cast<const v8s*>(&sW[1][ft * 16 + r][q * 8]);
      acc[ft] = __builtin_amdgcn_mfma_f32_16x16x32_bf16(ah, bh, acc[ft], 0, 0, 0);
      acc[ft] = __builtin_amdgcn_mfma_f32_16x16x32_bf16(ah, bl, acc[ft], 0, 0, 0);
    }
  }

#pragma unroll
  for (int ft = 0; ft < NF; ++ft) {
    int col = ft * 16 + r;
    if (col < F) {
      float bv = bias ? bias[col] : 0.f;
#pragma unroll
      for (int i = 0; i < 4; ++i) {
        int row = row0 + q * 4 + i;
        if (row < N) {
          float v = acc[ft][i] + bv;
          if (addin) v += bfh(addin[(size_t)row * F + col]);
          if (do_relu) v = fmaxf(v, 0.f);
          size_t o = (size_t)row * out_ld + col;
          if (OUTBF) ((uint16_t*)OUTP)[o] = rne16(v);
          else ((float*)OUTP)[o] = v;
        }
      }
    }
  }
}

// ---------------------------------------------------- final linear + logsoftmax
__global__ __launch_bounds__(256) void final_ls_kernel(
    const float* __restrict__ XCAT, const float* __restrict__ lpw,
    const float* __restrict__ lpb, float* __restrict__ out) {
  int wid = (blockIdx.x * 256 + threadIdx.x) >> 6;
  int lane = threadIdx.x & 63;
  if (wid >= N_NODES) return;
  const float* xr = XCAT + (size_t)wid * 80;
  float logit = -1e30f;
  if (lane < 40) {
    float s = lpb[lane];
    const float* wr = lpw + lane * 80;
#pragma unroll 8
    for (int k = 0; k < 80; ++k) s += xr[k] * wr[k];
    logit = s;
  }
  float m = logit;
#pragma unroll
  for (int d = 1; d < 64; d <<= 1) m = fmaxf(m, __shfl_xor(m, d));
  float e = (lane < 40) ? __expf(logit - m) : 0.f;
  float ssum = e;
#pragma unroll
  for (int d = 1; d < 64; d <<= 1) ssum += __shfl_xor(ssum, d);
  if (lane < 40)
    out[(size_t)wid * 40 + lane] = logit - m - __logf(ssum);
}

// ---------------------------------------------------------------- launcher
extern "C" void kernel_launch(void* const* d_in, const int* in_sizes, int n_in,
                              void* d_out, int out_size, void* d_ws, size_t ws_size,
                              hipStream_t stream) {
  const float* x      = (const float*)d_in[0];
  const int* src      = (const int*)d_in[1];
  const int* dst      = (const int*)d_in[2];
  const int* he_node  = (const int*)d_in[3];
  const int* he_edge  = (const int*)d_in[4];
  const float* s0wl = (const float*)d_in[5],  *s0wr = (const float*)d_in[6],  *s0b = (const float*)d_in[7];
  const float* s1wl = (const float*)d_in[8],  *s1wr = (const float*)d_in[9],  *s1b = (const float*)d_in[10];
  const float* s2wl = (const float*)d_in[11], *s2wr = (const float*)d_in[12], *s2b = (const float*)d_in[13];
  const float* h0w = (const float*)d_in[14], *h0b = (const float*)d_in[15];
  const float* h1w = (const float*)d_in[16], *h1b = (const float*)d_in[17];
  const float* h2w = (const float*)d_in[18], *h2b = (const float*)d_in[19];
  const float* h3w = (const float*)d_in[20], *h3b = (const float*)d_in[21];
  const float* h4w = (const float*)d_in[22], *h4b = (const float*)d_in[23];
  const float* lpw = (const float*)d_in[24], *lpb = (const float*)d_in[25];
  float* out = (float*)d_out;

  char* p = (char*)d_ws;
  auto carve = [&](size_t bytes) -> char* {
    char* r = p;
    p += (bytes + 255) & ~(size_t)255;
    return r;
  };
  int* cnt_dst  = (int*)carve((size_t)N_NODES * 4);
  int* adj_off  = (int*)carve((size_t)(N_NODES + 1) * 4);
  int* adj_cur  = (int*)carve((size_t)N_NODES * 4);
  int* adj_src  = (int*)carve((size_t)N_EDGE * 4);
  int* cnt_he   = (int*)carve((size_t)N_HE * 4);
  int* heg_off  = (int*)carve((size_t)(N_HE + 1) * 4);
  int* heg_cur  = (int*)carve((size_t)N_HE * 4);
  int* heg_node = (int*)carve((size_t)N_INC * 4);
  int* cnt_hn   = (int*)carve((size_t)N_NODES * 4);
  int* hng_off  = (int*)carve((size_t)(N_NODES + 1) * 4);
  int* hng_cur  = (int*)carve((size_t)N_NODES * 4);
  int* hng_edge = (int*)carve((size_t)N_INC * 4);
  float* deg_inv = (float*)carve((size_t)N_NODES * 4);
  float* binv    = (float*)carve((size_t)N_HE * 4);
  float* dinv    = (float*)carve((size_t)N_NODES * 4);
  uint16_t* Wh = (uint16_t*)carve((size_t)W_TOTAL * 2);
  uint16_t* Wl = (uint16_t*)carve((size_t)W_TOTAL * 2);
  uint16_t* XB = (uint16_t*)carve((size_t)N_NODES * 128 * 2);
  uint16_t* U  = (uint16_t*)carve((size_t)N_NODES * 128 * 2);
  uint16_t* NA = (uint16_t*)carve((size_t)N_NODES * 256 * 2);
  uint16_t* NB = (uint16_t*)carve((size_t)N_NODES * 256 * 2);
  uint16_t* NC = (uint16_t*)carve((size_t)N_NODES * 256 * 2);
  uint16_t* EF = (uint16_t*)carve((size_t)N_HE * 256 * 2);
  uint16_t* T40 = (uint16_t*)carve((size_t)N_NODES * 40 * 2);
  uint16_t* S40 = (uint16_t*)carve((size_t)N_NODES * 40 * 2);
  float* XCAT = (float*)carve((size_t)N_NODES * 80 * 4);

  const int GE = (N_EDGE + 255) / 256;
  const int GN = (N_NODES + 255) / 256;
  const int GL = (N_NODES + 63) / 64;

  // ---- CSR build + weight split + x conversion
  zero3_kernel<<<411, 256, 0, stream>>>(cnt_dst, N_NODES, cnt_he, N_HE, cnt_hn, N_NODES);
  hist_kernel<<<GE, 256, 0, stream>>>(dst, he_node, he_edge, cnt_dst, cnt_he, cnt_hn);
  scales_kernel<<<GN, 256, 0, stream>>>(cnt_dst, cnt_hn, cnt_he, deg_inv, dinv, binv);
  scan3_kernel<<<3, 1024, 0, stream>>>(cnt_dst, adj_off, adj_cur,
                                       cnt_he, heg_off, heg_cur,
                                       cnt_hn, hng_off, hng_cur);
  fill_kernel<<<GE, 256, 0, stream>>>(src, dst, he_node, he_edge,
                                      adj_cur, adj_src, heg_cur, heg_node,
                                      hng_cur, hng_edge);
  split_w_kernel<<<(W_TOTAL + 255) / 256, 256, 0, stream>>>(
      s0wl, s0wr, s1wl, s1wr, s2wl, s2wr, h0w, h1w, h2w, h3w, h4w, Wh, Wl);
  cvt_kernel<<<(N_NODES * 32 + 255) / 256, 256, 0, stream>>>(x, XB, N_NODES * 32);

  // ---- SAGE branch
  aggb_kernel<128><<<N_NODES, 64, 0, stream>>>(adj_off, adj_src, deg_inv, XB, U);
  lin2b_kernel<128, 128, 256, true><<<GL, 256, 0, stream>>>(
      U, Wh + 0, Wl + 0, XB, Wh + 32768, Wl + 32768, s0b, nullptr, NA, 256, N_NODES, 1);
  aggb_kernel<256><<<N_NODES, 64, 0, stream>>>(adj_off, adj_src, deg_inv, NA, NB);
  lin2b_kernel<256, 256, 256, true><<<GL, 256, 0, stream>>>(
      NB, Wh + 65536, Wl + 65536, NA, Wh + 131072, Wl + 131072, s1b, nullptr, NC, 256, N_NODES, 1);
  lin2b_kernel<256, 0, 40, true><<<GL, 256, 0, stream>>>(
      NC, Wh + 196608, Wl + 196608, nullptr, nullptr, nullptr, nullptr, nullptr, T40, 40, N_NODES, 0);
  aggb_kernel<40><<<N_NODES, 64, 0, stream>>>(adj_off, adj_src, deg_inv, T40, S40);
  lin2b_kernel<256, 0, 40, false><<<GL, 256, 0, stream>>>(
      NC, Wh + 206848, Wl + 206848, nullptr, nullptr, nullptr, s2b, S40, XCAT, 80, N_NODES, 0);

  // ---- Hypergraph branch (g in NC; per layer NC -> EF -> NB -> NC)
  aggb_kernel<128><<<N_HE, 64, 0, stream>>>(heg_off, heg_node, binv, XB, EF);
  aggb_kernel<128><<<N_NODES, 64, 0, stream>>>(hng_off, hng_edge, dinv, EF, U);
  lin2b_kernel<128, 0, 256, true><<<GL, 256, 0, stream>>>(
      U, Wh + 217088, Wl + 217088, nullptr, nullptr, nullptr, h0b, nullptr, NC, 256, N_NODES, 1);
  aggb_kernel<256><<<N_HE, 64, 0, stream>>>(heg_off, heg_node, binv, NC, EF);
  aggb_kernel<256><<<N_NODES, 64, 0, stream>>>(hng_off, hng_edge, dinv, EF, NB);
  lin2b_kernel<256, 0, 256, true><<<GL, 256, 0, stream>>>(
      NB, Wh + 249856, Wl + 249856, nullptr, nullptr, nullptr, h1b, nullptr, NC, 256, N_NODES, 1);
  aggb_kernel<256><<<N_HE, 64, 0, stream>>>(heg_off, heg_node, binv, NC, EF);
  aggb_kernel<256><<<N_NODES, 64, 0, stream>>>(hng_off, hng_edge, dinv, EF, NB);
  lin2b_kernel<256, 0, 256, true><<<GL, 256, 0, stream>>>(
      NB, Wh + 315392, Wl + 315392, nullptr, nullptr, nullptr, h2b, nullptr, NC, 256, N_NODES, 1);
  aggb_kernel<256><<<N_HE, 64, 0, stream>>>(heg_off, heg_node, binv, NC, EF);
  aggb_kernel<256><<<N_NODES, 64, 0, stream>>>(hng_off, hng_edge, dinv, EF, NB);
  lin2b_kernel<256, 0, 256, true><<<GL, 256, 0, stream>>>(
      NB, Wh + 380928, Wl + 380928, nullptr, nullptr, nullptr, h3b, nullptr, NC, 256, N_NODES, 1);
  lin2b_kernel<256, 0, 40, true><<<GL, 256, 0, stream>>>(
      NC, Wh + 446464, Wl + 446464, nullptr, nullptr, nullptr, nullptr, nullptr, T40, 40, N_NODES, 0);
  aggb_kernel<40><<<N_HE, 64, 0, stream>>>(heg_off, heg_node, binv, T40, EF);
  agg40b_kernel<<<N_NODES, 64, 0, stream>>>(hng_off, hng_edge, dinv, EF, h4b, XCAT);

  // ---- final linear + log_softmax
  final_ls_kernel<<<(N_NODES + 3) / 4, 256, 0, stream>>>(XCAT, lpw, lpb, out);
}

// Round 6
// 1054.386 us; speedup vs baseline: 2.0596x; 1.0082x over previous
//
#include <hip/hip_runtime.h>
#include <hip/hip_bf16.h>
#include <cstdint>
#include <cstddef>

typedef __hip_bfloat16 bf16;
typedef short v8s __attribute__((ext_vector_type(8)));
typedef float v4f __attribute__((ext_vector_type(4)));
typedef unsigned short v4u __attribute__((ext_vector_type(4)));
typedef unsigned short v2u __attribute__((ext_vector_type(2)));

#define N_NODES 50000
#define N_HE    5000
#define N_EDGE  800000
#define N_INC   400000

__device__ inline float bfh(uint32_t u) { return __uint_as_float(u << 16); }
__device__ inline uint16_t rne16(float f) {
  uint32_t u = __float_as_uint(f);
  return (uint16_t)((u + 0x7FFFu + ((u >> 16) & 1u)) >> 16);
}

// ---------------------------------------------------------------- CSR build
__global__ void zero3_kernel(int* a, int na, int* b, int nb, int* c, int nc) {
  int total = na + nb + nc;
  for (int i = blockIdx.x * blockDim.x + threadIdx.x; i < total;
       i += gridDim.x * blockDim.x) {
    if (i < na) a[i] = 0;
    else if (i < na + nb) b[i - na] = 0;
    else c[i - na - nb] = 0;
  }
}

__global__ void hist_kernel(const int* __restrict__ dst,
                            const int* __restrict__ he_node,
                            const int* __restrict__ he_edge,
                            int* cnt_dst, int* cnt_he, int* cnt_hn) {
  int i = blockIdx.x * blockDim.x + threadIdx.x;
  if (i < N_EDGE) atomicAdd(&cnt_dst[dst[i]], 1);
  if (i < N_INC) {
    atomicAdd(&cnt_he[he_edge[i]], 1);
    atomicAdd(&cnt_hn[he_node[i]], 1);
  }
}

__global__ void scales_kernel(const int* cnt_dst, const int* cnt_hn,
                              const int* cnt_he,
                              float* deg_inv, float* dinv, float* binv) {
  int i = blockIdx.x * blockDim.x + threadIdx.x;
  if (i < N_NODES) {
    int d = cnt_dst[i];
    deg_inv[i] = 1.0f / (float)(d > 1 ? d : 1);
    int h = cnt_hn[i];
    dinv[i] = h > 0 ? 1.0f / (float)h : 0.0f;
  }
  if (i < N_HE) {
    int e = cnt_he[i];
    binv[i] = e > 0 ? 1.0f / (float)e : 0.0f;
  }
}

__global__ void scan3_kernel(const int* cnt_dst, int* adj_off, int* adj_cur,
                             const int* cnt_he, int* heg_off, int* heg_cur,
                             const int* cnt_hn, int* hng_off, int* hng_cur) {
  const int* cnt; int* off; int* cur; int n;
  if (blockIdx.x == 0)      { cnt = cnt_dst; off = adj_off; cur = adj_cur; n = N_NODES; }
  else if (blockIdx.x == 1) { cnt = cnt_he;  off = heg_off; cur = heg_cur; n = N_HE; }
  else                      { cnt = cnt_hn;  off = hng_off; cur = hng_cur; n = N_NODES; }
  __shared__ int buf[1024];
  int t = threadIdx.x;
  int carry = 0;
  for (int base = 0; base < n; base += 1024) {
    int i = base + t;
    int v = (i < n) ? cnt[i] : 0;
    buf[t] = v;
    __syncthreads();
    for (int d = 1; d < 1024; d <<= 1) {
      int x = (t >= d) ? buf[t - d] : 0;
      __syncthreads();
      buf[t] += x;
      __syncthreads();
    }
    int excl = buf[t] - v;
    if (i < n) { off[i] = carry + excl; cur[i] = carry + excl; }
    int total = buf[1023];
    __syncthreads();
    carry += total;
  }
  if (t == 0) off[n] = carry;
}

__global__ void fill_kernel(const int* __restrict__ src, const int* __restrict__ dst,
                            const int* __restrict__ he_node, const int* __restrict__ he_edge,
                            int* adj_cur, int* adj_src,
                            int* heg_cur, int* heg_node,
                            int* hng_cur, int* hng_edge) {
  int i = blockIdx.x * blockDim.x + threadIdx.x;
  if (i < N_EDGE) {
    int p = atomicAdd(&adj_cur[dst[i]], 1);
    adj_src[p] = src[i];
  }
  if (i < N_INC) {
    int p = atomicAdd(&heg_cur[he_edge[i]], 1);
    heg_node[p] = he_node[i];
    int p2 = atomicAdd(&hng_cur[he_node[i]], 1);
    hng_edge[p2] = he_edge[i];
  }
}

// ---------------------------------------------------- weight hi/lo bf16 split
#define W_TOTAL 456704
__global__ void split_w_kernel(const float* s0wl, const float* s0wr,
                               const float* s1wl, const float* s1wr,
                               const float* s2wl, const float* s2wr,
                               const float* h0w, const float* h1w,
                               const float* h2w, const float* h3w,
                               const float* h4w,
                               uint16_t* hi, uint16_t* lo) {
  int i = blockIdx.x * blockDim.x + threadIdx.x;
  if (i >= W_TOTAL) return;
  const float* src; int base;
  if (i < 32768)       { src = s0wl; base = 0; }
  else if (i < 65536)  { src = s0wr; base = 32768; }
  else if (i < 131072) { src = s1wl; base = 65536; }
  else if (i < 196608) { src = s1wr; base = 131072; }
  else if (i < 206848) { src = s2wl; base = 196608; }
  else if (i < 217088) { src = s2wr; base = 206848; }
  else if (i < 249856) { src = h0w;  base = 217088; }
  else if (i < 315392) { src = h1w;  base = 249856; }
  else if (i < 380928) { src = h2w;  base = 315392; }
  else if (i < 446464) { src = h3w;  base = 380928; }
  else                 { src = h4w;  base = 446464; }
  float v = src[i - base];
  uint16_t hb = rne16(v);
  float lf = v - bfh(hb);
  hi[i] = hb;
  lo[i] = rne16(lf);
}

// ---------------------------------------------------------- x f32 -> bf16
__global__ void cvt_kernel(const float* __restrict__ X, uint16_t* __restrict__ O, int n4) {
  int i = blockIdx.x * blockDim.x + threadIdx.x;
  if (i >= n4) return;
  v4f v = *((const v4f*)X + i);
  v4u o;
  o[0] = rne16(v[0]); o[1] = rne16(v[1]); o[2] = rne16(v[2]); o[3] = rne16(v[3]);
  *((v4u*)O + i) = o;
}

// ------------------------------------------- CSR gather-mean over bf16 rows
// OUT[row,:] = rne16( act( scale[row] * sum_j X[idx[j],:] + bias ) )
// bias==nullptr -> plain mean. do_relu only honored when bias given.
template <int F>
__global__ void aggb_kernel(const int* __restrict__ off, const int* __restrict__ idx,
                            const float* __restrict__ scale,
                            const uint16_t* __restrict__ X,
                            uint16_t* __restrict__ OUT,
                            const float* __restrict__ bias, int do_relu) {
  constexpr int VEC = (F >= 256) ? 4 : 2;
  int row = blockIdx.x;
  int t = threadIdx.x;
  if (t * VEC >= F) return;
  int j0 = off[row], j1 = off[row + 1];
  float sc = scale[row];
  float acc[VEC];
#pragma unroll
  for (int k = 0; k < VEC; ++k) acc[k] = 0.f;

  int j = j0;
  for (; j + 3 < j1; j += 4) {
    int s0 = idx[j], s1 = idx[j + 1], s2 = idx[j + 2], s3 = idx[j + 3];
    if (VEC == 4) {
      v4u a = *(const v4u*)(X + (size_t)s0 * F + t * 4);
      v4u b = *(const v4u*)(X + (size_t)s1 * F + t * 4);
      v4u c = *(const v4u*)(X + (size_t)s2 * F + t * 4);
      v4u d = *(const v4u*)(X + (size_t)s3 * F + t * 4);
#pragma unroll
      for (int k = 0; k < 4; ++k)
        acc[k] += bfh(a[k]) + bfh(b[k]) + bfh(c[k]) + bfh(d[k]);
    } else {
      v2u a = *(const v2u*)(X + (size_t)s0 * F + t * 2);
      v2u b = *(const v2u*)(X + (size_t)s1 * F + t * 2);
      v2u c = *(const v2u*)(X + (size_t)s2 * F + t * 2);
      v2u d = *(const v2u*)(X + (size_t)s3 * F + t * 2);
#pragma unroll
      for (int k = 0; k < 2; ++k)
        acc[k] += bfh(a[k]) + bfh(b[k]) + bfh(c[k]) + bfh(d[k]);
    }
  }
  for (; j < j1; ++j) {
    int s = idx[j];
    if (VEC == 4) {
      v4u a = *(const v4u*)(X + (size_t)s * F + t * 4);
#pragma unroll
      for (int k = 0; k < 4; ++k) acc[k] += bfh(a[k]);
    } else {
      v2u a = *(const v2u*)(X + (size_t)s * F + t * 2);
#pragma unroll
      for (int k = 0; k < 2; ++k) acc[k] += bfh(a[k]);
    }
  }

  if (VEC == 4) {
    v4u o;
#pragma unroll
    for (int k = 0; k < 4; ++k) {
      float v = acc[k] * sc;
      if (bias) { v += bias[t * 4 + k]; if (do_relu) v = fmaxf(v, 0.f); }
      o[k] = rne16(v);
    }
    *(v4u*)(OUT + (size_t)row * F + t * 4) = o;
  } else {
    v2u o;
#pragma unroll
    for (int k = 0; k < 2; ++k) {
      float v = acc[k] * sc;
      if (bias) { v += bias[t * 2 + k]; if (do_relu) v = fmaxf(v, 0.f); }
      o[k] = rne16(v);
    }
    *(v2u*)(OUT + (size_t)row * F + t * 2) = o;
  }
}

// Final hyper agg (F=40) fused with bias, f32 out into XCAT[:,40:].
__global__ void agg40b_kernel(const int* __restrict__ off, const int* __restrict__ idx,
                              const float* __restrict__ scale,
                              const uint16_t* __restrict__ EF40,
                              const float* __restrict__ bias,
                              float* __restrict__ XCAT) {
  int row = blockIdx.x;
  int t = threadIdx.x;
  if (t >= 20) return;
  int j0 = off[row], j1 = off[row + 1];
  float sc = scale[row];
  float a0 = 0.f, a1 = 0.f;
  for (int j = j0; j < j1; ++j) {
    int s = idx[j];
    v2u v = *(const v2u*)(EF40 + (size_t)s * 40 + t * 2);
    a0 += bfh(v[0]);
    a1 += bfh(v[1]);
  }
  XCAT[(size_t)row * 80 + 40 + t * 2]     = a0 * sc + bias[t * 2];
  XCAT[(size_t)row * 80 + 40 + t * 2 + 1] = a1 * sc + bias[t * 2 + 1];
}

// ------------------------------------- bf16-A, split-W LDS-staged MFMA GEMM
// OUT[n,f] = act( X1[n,:]·W1[f,:] (+ X2[n,:]·W2[f,:]) + bias[f] + addin[n,f] )
// A exact bf16; W = Wh + Wl (hi/lo split, f32-accurate).
// A/B frag: row|col = lane&15, k = (lane>>4)*8+j.  C/D: col = lane&15,
// row = (lane>>4)*4 + reg  (verified gfx950 mappings).
template <int K1, int K2, int F, bool OUTBF>
__global__ __launch_bounds__(256, 4) void lin2b_kernel(
    const uint16_t* __restrict__ X1, const uint16_t* __restrict__ W1h, const uint16_t* __restrict__ W1l,
    const uint16_t* __restrict__ X2, const uint16_t* __restrict__ W2h, const uint16_t* __restrict__ W2l,
    const float* __restrict__ bias, const uint16_t* __restrict__ addin,
    void* __restrict__ OUTP, int out_ld, int N, int do_relu) {
  constexpr int FP  = (F + 15) & ~15;
  constexpr int NF  = FP / 16;
  constexpr int NC1 = K1 / 32;
  constexpr int NCH = (K1 + (K2 > 0 ? K2 : 0)) / 32;
  constexpr int RS  = 40;
  __shared__ short sW[2][FP][RS];

  int tid  = threadIdx.x;
  int wave = tid >> 6, lane = tid & 63;
  int r = lane & 15, q = lane >> 4;
  int row0 = blockIdx.x * 64 + wave * 16;
  int rowA = row0 + r; if (rowA > N - 1) rowA = N - 1;

  int srow = tid >> 2;
  int sj   = tid & 3;

  v4f acc[NF];
#pragma unroll
  for (int i = 0; i < NF; ++i) acc[i] = (v4f){0.f, 0.f, 0.f, 0.f};

  for (int c = 0; c < NCH; ++c) {
    const bool first = (K2 == 0) || (c < NC1);
    const uint16_t* Wh = first ? W1h : W2h;
    const uint16_t* Wl = first ? W1l : W2l;
    const uint16_t* Xs = first ? X1 : X2;
    const int K  = first ? K1 : K2;
    const int kc = (first ? c : c - NC1) * 32;

    if (c) __syncthreads();
    const v8s zz = {0, 0, 0, 0, 0, 0, 0, 0};
#pragma unroll
    for (int pass = 0; pass < (FP + 63) / 64; ++pass) {
      int row = srow + pass * 64;
      if (row < FP) {
        v8s hv = zz, lv = zz;
        if (row < F) {
          hv = *reinterpret_cast<const v8s*>(Wh + (size_t)row * K + kc + sj * 8);
          lv = *reinterpret_cast<const v8s*>(Wl + (size_t)row * K + kc + sj * 8);
        }
        *reinterpret_cast<v8s*>(&sW[0][row][sj * 8]) = hv;
        *reinterpret_cast<v8s*>(&sW[1][row][sj * 8]) = lv;
      }
    }
    v8s ah = *reinterpret_cast<const v8s*>(Xs + (size_t)rowA * K + kc + q * 8);
    __syncthreads();
#pragma unroll
    for (int ft = 0; ft < NF; ++ft) {
      v8s bh = *reinterpret_cast<const v8s*>(&sW[0][ft * 16 + r][q * 8]);
      v8s bl = *reinterpret_cast<const v8s*>(&sW[1][ft * 16 + r][q * 8]);
      acc[ft] = __builtin_amdgcn_mfma_f32_16x16x32_bf16(ah, bh, acc[ft], 0, 0, 0);
      acc[ft] = __builtin_amdgcn_mfma_f32_16x16x32_bf16(ah, bl, acc[ft], 0, 0, 0);
    }
  }

#pragma unroll
  for (int ft = 0; ft < NF; ++ft) {
    int col = ft * 16 + r;
    if (col < F) {
      float bv = bias ? bias[col] : 0.f;
#pragma unroll
      for (int i = 0; i < 4; ++i) {
        int row = row0 + q * 4 + i;
        if (row < N) {
          float v = acc[ft][i] + bv;
          if (addin) v += bfh(addin[(size_t)row * F + col]);
          if (do_relu) v = fmaxf(v, 0.f);
          size_t o = (size_t)row * out_ld + col;
          if (OUTBF) ((uint16_t*)OUTP)[o] = rne16(v);
          else ((float*)OUTP)[o] = v;
        }
      }
    }
  }
}

// ---------------------------------------------------- final linear + logsoftmax
__global__ __launch_bounds__(256) void final_ls_kernel(
    const float* __restrict__ XCAT, const float* __restrict__ lpw,
    const float* __restrict__ lpb, float* __restrict__ out) {
  int wid = (blockIdx.x * 256 + threadIdx.x) >> 6;
  int lane = threadIdx.x & 63;
  if (wid >= N_NODES) return;
  const float* xr = XCAT + (size_t)wid * 80;
  float logit = -1e30f;
  if (lane < 40) {
    float s = lpb[lane];
    const float* wr = lpw + lane * 80;
#pragma unroll 8
    for (int k = 0; k < 80; ++k) s += xr[k] * wr[k];
    logit = s;
  }
  float m = logit;
#pragma unroll
  for (int d = 1; d < 64; d <<= 1) m = fmaxf(m, __shfl_xor(m, d));
  float e = (lane < 40) ? __expf(logit - m) : 0.f;
  float ssum = e;
#pragma unroll
  for (int d = 1; d < 64; d <<= 1) ssum += __shfl_xor(ssum, d);
  if (lane < 40)
    out[(size_t)wid * 40 + lane] = logit - m - __logf(ssum);
}

// ---------------------------------------------------------------- launcher
extern "C" void kernel_launch(void* const* d_in, const int* in_sizes, int n_in,
                              void* d_out, int out_size, void* d_ws, size_t ws_size,
                              hipStream_t stream) {
  const float* x      = (const float*)d_in[0];
  const int* src      = (const int*)d_in[1];
  const int* dst      = (const int*)d_in[2];
  const int* he_node  = (const int*)d_in[3];
  const int* he_edge  = (const int*)d_in[4];
  const float* s0wl = (const float*)d_in[5],  *s0wr = (const float*)d_in[6],  *s0b = (const float*)d_in[7];
  const float* s1wl = (const float*)d_in[8],  *s1wr = (const float*)d_in[9],  *s1b = (const float*)d_in[10];
  const float* s2wl = (const float*)d_in[11], *s2wr = (const float*)d_in[12], *s2b = (const float*)d_in[13];
  const float* h0w = (const float*)d_in[14], *h0b = (const float*)d_in[15];
  const float* h1w = (const float*)d_in[16], *h1b = (const float*)d_in[17];
  const float* h2w = (const float*)d_in[18], *h2b = (const float*)d_in[19];
  const float* h3w = (const float*)d_in[20], *h3b = (const float*)d_in[21];
  const float* h4w = (const float*)d_in[22], *h4b = (const float*)d_in[23];
  const float* lpw = (const float*)d_in[24], *lpb = (const float*)d_in[25];
  float* out = (float*)d_out;

  char* p = (char*)d_ws;
  auto carve = [&](size_t bytes) -> char* {
    char* r = p;
    p += (bytes + 255) & ~(size_t)255;
    return r;
  };
  int* cnt_dst  = (int*)carve((size_t)N_NODES * 4);
  int* adj_off  = (int*)carve((size_t)(N_NODES + 1) * 4);
  int* adj_cur  = (int*)carve((size_t)N_NODES * 4);
  int* adj_src  = (int*)carve((size_t)N_EDGE * 4);
  int* cnt_he   = (int*)carve((size_t)N_HE * 4);
  int* heg_off  = (int*)carve((size_t)(N_HE + 1) * 4);
  int* heg_cur  = (int*)carve((size_t)N_HE * 4);
  int* heg_node = (int*)carve((size_t)N_INC * 4);
  int* cnt_hn   = (int*)carve((size_t)N_NODES * 4);
  int* hng_off  = (int*)carve((size_t)(N_NODES + 1) * 4);
  int* hng_cur  = (int*)carve((size_t)N_NODES * 4);
  int* hng_edge = (int*)carve((size_t)N_INC * 4);
  float* deg_inv = (float*)carve((size_t)N_NODES * 4);
  float* binv    = (float*)carve((size_t)N_HE * 4);
  float* dinv    = (float*)carve((size_t)N_NODES * 4);
  uint16_t* Wh = (uint16_t*)carve((size_t)W_TOTAL * 2);
  uint16_t* Wl = (uint16_t*)carve((size_t)W_TOTAL * 2);
  uint16_t* XB = (uint16_t*)carve((size_t)N_NODES * 128 * 2);
  uint16_t* U  = (uint16_t*)carve((size_t)N_NODES * 128 * 2);
  uint16_t* NA = (uint16_t*)carve((size_t)N_NODES * 256 * 2);
  uint16_t* NB = (uint16_t*)carve((size_t)N_NODES * 256 * 2);
  uint16_t* NC = (uint16_t*)carve((size_t)N_NODES * 256 * 2);
  uint16_t* EFa = (uint16_t*)carve((size_t)N_HE * 256 * 2);
  uint16_t* EFb = (uint16_t*)carve((size_t)N_HE * 256 * 2);
  uint16_t* T40 = (uint16_t*)carve((size_t)N_NODES * 40 * 2);
  uint16_t* S40 = (uint16_t*)carve((size_t)N_NODES * 40 * 2);
  float* XCAT = (float*)carve((size_t)N_NODES * 80 * 4);

  const int GE = (N_EDGE + 255) / 256;
  const int GN = (N_NODES + 255) / 256;
  const int GL = (N_NODES + 63) / 64;
  const int GS = (N_HE + 63) / 64;        // small (hyperedge-row) GEMMs

  // ---- CSR build + weight split + x conversion
  zero3_kernel<<<411, 256, 0, stream>>>(cnt_dst, N_NODES, cnt_he, N_HE, cnt_hn, N_NODES);
  hist_kernel<<<GE, 256, 0, stream>>>(dst, he_node, he_edge, cnt_dst, cnt_he, cnt_hn);
  scales_kernel<<<GN, 256, 0, stream>>>(cnt_dst, cnt_hn, cnt_he, deg_inv, dinv, binv);
  scan3_kernel<<<3, 1024, 0, stream>>>(cnt_dst, adj_off, adj_cur,
                                       cnt_he, heg_off, heg_cur,
                                       cnt_hn, hng_off, hng_cur);
  fill_kernel<<<GE, 256, 0, stream>>>(src, dst, he_node, he_edge,
                                      adj_cur, adj_src, heg_cur, heg_node,
                                      hng_cur, hng_edge);
  split_w_kernel<<<(W_TOTAL + 255) / 256, 256, 0, stream>>>(
      s0wl, s0wr, s1wl, s1wr, s2wl, s2wr, h0w, h1w, h2w, h3w, h4w, Wh, Wl);
  cvt_kernel<<<(N_NODES * 32 + 255) / 256, 256, 0, stream>>>(x, XB, N_NODES * 32);

  // ---- SAGE branch
  aggb_kernel<128><<<N_NODES, 64, 0, stream>>>(adj_off, adj_src, deg_inv, XB, U, nullptr, 0);
  lin2b_kernel<128, 128, 256, true><<<GL, 256, 0, stream>>>(
      U, Wh + 0, Wl + 0, XB, Wh + 32768, Wl + 32768, s0b, nullptr, NA, 256, N_NODES, 1);
  aggb_kernel<256><<<N_NODES, 64, 0, stream>>>(adj_off, adj_src, deg_inv, NA, NB, nullptr, 0);
  lin2b_kernel<256, 256, 256, true><<<GL, 256, 0, stream>>>(
      NB, Wh + 65536, Wl + 65536, NA, Wh + 131072, Wl + 131072, s1b, nullptr, NC, 256, N_NODES, 1);
  lin2b_kernel<256, 0, 40, true><<<GL, 256, 0, stream>>>(
      NC, Wh + 196608, Wl + 196608, nullptr, nullptr, nullptr, nullptr, nullptr, T40, 40, N_NODES, 0);
  aggb_kernel<40><<<N_NODES, 64, 0, stream>>>(adj_off, adj_src, deg_inv, T40, S40, nullptr, 0);
  lin2b_kernel<256, 0, 40, false><<<GL, 256, 0, stream>>>(
      NC, Wh + 206848, Wl + 206848, nullptr, nullptr, nullptr, s2b, S40, XCAT, 80, N_NODES, 0);

  // ---- Hypergraph branch: heagg -> tiny GEMM (5000 rows) -> nodeagg+bias+relu
  // layer 0 (K=128)
  aggb_kernel<128><<<N_HE, 64, 0, stream>>>(heg_off, heg_node, binv, XB, EFa, nullptr, 0);
  lin2b_kernel<128, 0, 256, true><<<GS, 256, 0, stream>>>(
      EFa, Wh + 217088, Wl + 217088, nullptr, nullptr, nullptr, nullptr, nullptr, EFb, 256, N_HE, 0);
  aggb_kernel<256><<<N_NODES, 64, 0, stream>>>(hng_off, hng_edge, dinv, EFb, NC, h0b, 1);
  // layers 1..3 (K=256)
  aggb_kernel<256><<<N_HE, 64, 0, stream>>>(heg_off, heg_node, binv, NC, EFa, nullptr, 0);
  lin2b_kernel<256, 0, 256, true><<<GS, 256, 0, stream>>>(
      EFa, Wh + 249856, Wl + 249856, nullptr, nullptr, nullptr, nullptr, nullptr, EFb, 256, N_HE, 0);
  aggb_kernel<256><<<N_NODES, 64, 0, stream>>>(hng_off, hng_edge, dinv, EFb, NC, h1b, 1);

  aggb_kernel<256><<<N_HE, 64, 0, stream>>>(heg_off, heg_node, binv, NC, EFa, nullptr, 0);
  lin2b_kernel<256, 0, 256, true><<<GS, 256, 0, stream>>>(
      EFa, Wh + 315392, Wl + 315392, nullptr, nullptr, nullptr, nullptr, nullptr, EFb, 256, N_HE, 0);
  aggb_kernel<256><<<N_NODES, 64, 0, stream>>>(hng_off, hng_edge, dinv, EFb, NC, h2b, 1);

  aggb_kernel<256><<<N_HE, 64, 0, stream>>>(heg_off, heg_node, binv, NC, EFa, nullptr, 0);
  lin2b_kernel<256, 0, 256, true><<<GS, 256, 0, stream>>>(
      EFa, Wh + 380928, Wl + 380928, nullptr, nullptr, nullptr, nullptr, nullptr, EFb, 256, N_HE, 0);
  aggb_kernel<256><<<N_NODES, 64, 0, stream>>>(hng_off, hng_edge, dinv, EFb, NC, h3b, 1);
  // layer 4 (F=40): transform node features first (cheap), then aggregate
  lin2b_kernel<256, 0, 40, true><<<GL, 256, 0, stream>>>(
      NC, Wh + 446464, Wl + 446464, nullptr, nullptr, nullptr, nullptr, nullptr, T40, 40, N_NODES, 0);
  aggb_kernel<40><<<N_HE, 64, 0, stream>>>(heg_off, heg_node, binv, T40, EFa, nullptr, 0);
  agg40b_kernel<<<N_NODES, 64, 0, stream>>>(hng_off, hng_edge, dinv, EFa, h4b, XCAT);

  // ---- final linear + log_softmax
  final_ls_kernel<<<(N_NODES + 3) / 4, 256, 0, stream>>>(XCAT, lpw, lpb, out);
}